// Round 5
// baseline (6864.400 us; speedup 1.0000x reference)
//
#include <hip/hip_runtime.h>
#include <cstdint>
#include <cstddef>

#define B_ROWS 32768
#define ZD 64
#define XD 256
#define HID 512
#define T_STEPS 8
#define MULT 23
#define MPAD 24
#define NOUT 1472
#define NPAD 1536      // 64 * MPAD
#define K1 320         // ZD + XD
#define PSTRIDE 200    // padded row stride (ushorts) for p-tile in LDS (400B = 25*16B)

typedef float f32x4 __attribute__((ext_vector_type(4)));
typedef short s16x8 __attribute__((ext_vector_type(8)));

__device__ __forceinline__ unsigned short f2bf(float f) {
  unsigned int u = __float_as_uint(f);
  u = (u + 0x7FFFu + ((u >> 16) & 1u)) >> 16;   // RNE, no NaN inputs here
  return (unsigned short)u;
}
__device__ __forceinline__ float bf2f(unsigned short s) {
  return __uint_as_float(((unsigned int)s) << 16);
}

// Degree-sort permutation of the hidden dim. deg(i) = (i%63)+1; count(g) = 9 (g<=8) else 8.
__device__ __forceinline__ int permP(int n) {
  return (n < 72) ? (n / 9) + 63 * (n % 9)
                  : ((n - 72) >> 3) + 8 + 63 * ((n - 72) & 7);
}
__device__ __forceinline__ int degP(int n) {
  return (n < 72) ? (n / 9) + 1 : ((n - 72) >> 3) + 9;
}

// ---------------- prep kernels (masks folded, degree-permuted, bf16) ----------------

__global__ void prep_w1cat(const float* __restrict__ W1, const float* __restrict__ Wc,
                           unsigned short* __restrict__ o) {
  int i = blockIdx.x * 256 + threadIdx.x;
  if (i >= T_STEPS * HID * K1) return;
  int t = i / (HID * K1);
  int r = i - t * (HID * K1);
  int n = r / K1;          // permuted hidden row
  int k = r - n * K1;
  int on = permP(n);
  float v;
  if (k < ZD) {  // m1: h_deg >= z_deg  <->  (on%63) >= k
    v = ((on % 63) >= k) ? W1[((size_t)t * HID + on) * ZD + k] : 0.0f;
  } else {
    v = Wc[((size_t)t * HID + on) * XD + (k - ZD)];
  }
  o[i] = f2bf(v);
}

__global__ void prep_w2(const float* __restrict__ W2, unsigned short* __restrict__ o) {
  int i = blockIdx.x * 256 + threadIdx.x;
  if (i >= T_STEPS * HID * HID) return;
  int t = i / (HID * HID);
  int r = i - t * (HID * HID);
  int n = r / HID;         // permuted out
  int k = r - n * HID;     // permuted in
  float v = 0.0f;
  if (degP(n) >= degP(k))  // m2: out_deg >= in_deg
    v = W2[((size_t)t * HID + permP(n)) * HID + permP(k)];
  o[i] = f2bf(v);
}

// W3: MPAD=24 row layout (row n = d*24 + jj, jj==23 zero), columns degree-permuted.
__global__ void prep_w3(const float* __restrict__ W3, unsigned short* __restrict__ o) {
  int i = blockIdx.x * 256 + threadIdx.x;
  if (i >= T_STEPS * NPAD * HID) return;
  int t = i / (NPAD * HID);
  int r = i - t * (NPAD * HID);
  int n = r / HID;
  int k = r - n * HID;     // permuted in
  int d = n / MPAD;
  int jj = n - d * MPAD;
  float v = 0.0f;
  if (jj < MULT && d >= degP(k))   // m3: o_deg(d+1) > h_deg  <->  h_deg <= d
    v = W3[((size_t)t * NOUT + d * MULT + jj) * HID + permP(k)];
  o[i] = f2bf(v);
}

__global__ void prep_bias(const float* __restrict__ b1, const float* __restrict__ bc,
                          const float* __restrict__ b2, const float* __restrict__ b3,
                          float* __restrict__ ob1, float* __restrict__ ob2,
                          float* __restrict__ ob3) {
  int i = blockIdx.x * 256 + threadIdx.x;
  if (i < T_STEPS * HID) {
    int t = i / HID, n = i - t * HID;
    int on = permP(n);
    ob1[i] = b1[(size_t)t * HID + on] + bc[(size_t)t * HID + on];
  } else if (i < 2 * T_STEPS * HID) {
    int j = i - T_STEPS * HID;
    int t = j / HID, n = j - t * HID;
    ob2[j] = b2[(size_t)t * HID + permP(n)];
  } else {
    int j = i - 2 * T_STEPS * HID;
    if (j < T_STEPS * NPAD) {
      int t = j / NPAD;
      int n = j - t * NPAD;
      int d = n / MPAD;
      int jj = n - d * MPAD;
      ob3[j] = (jj < MULT) ? b3[(size_t)t * NOUT + d * MULT + jj] : 0.0f;
    }
  }
}

__global__ void prep_x(const float* __restrict__ x, unsigned short* __restrict__ A1) {
  int i = blockIdx.x * 256 + threadIdx.x;
  if (i >= B_ROWS * XD) return;
  int b = i >> 8;
  int j = i & 255;
  A1[(size_t)b * K1 + ZD + j] = f2bf(x[i]);
}

__global__ void prep_init(const float* __restrict__ z, unsigned short* __restrict__ A1,
                          float* __restrict__ curf, float* __restrict__ lad) {
  int i = blockIdx.x * 256 + threadIdx.x;
  if (i >= B_ROWS * ZD) return;
  int b = i >> 6;
  int d = i & 63;
  float zv = z[i];
  A1[(size_t)b * K1 + d] = f2bf(zv);
  curf[i] = zv;
  if (d == 0) lad[b] = 0.0f;
}

// ---------------- shared GEMM machinery ----------------

#define ASYNC16(gp, lp) __builtin_amdgcn_global_load_lds( \
    (__attribute__((address_space(1))) unsigned int*)(gp), \
    (__attribute__((address_space(3))) unsigned int*)(lp), 16, 0, 0)

// ---------------- GEMM1/2: C[M,512] = A[M,K]@W[512,K]^T + bias, opt relu ----------
// grid MUST be (4, 256). tri=1: triangular K_eff = min(K, 192+n0) (gemm2 schedule).

__global__ __launch_bounds__(256, 2) void gemm_bias(
    const unsigned short* __restrict__ A,
    const unsigned short* __restrict__ Bw,
    const float* __restrict__ bias,
    unsigned short* __restrict__ C,
    int M, int N, int K, int relu, int tri)
{
  __shared__ alignas(16) unsigned short lA[128 * 32];
  __shared__ alignas(16) unsigned short lB[128 * 32];

  const int tid  = threadIdx.x;
  const int lane = tid & 63;
  const int wave = tid >> 6;

  const int lin = blockIdx.y * 4 + blockIdx.x;
  const int xcd = lin & 7;
  const int loc = lin >> 3;
  const int m0 = (xcd * 32 + (loc >> 2)) * 128;
  const int n0 = (loc & 3) * 128;
  const int Keff = tri ? min(K, 192 + n0) : K;

  const int wm = (wave >> 1) * 64;
  const int wn = (wave & 1) * 64;

  const int f    = tid * 16;
  const int row0 = f >> 6;       // 64B per 32-elem row
  const int colb = f & 63;

  char* gA0 = (char*)A  + ((size_t)(m0 + row0) * K) * 2 + colb;
  char* gA1 = gA0 + (size_t)64 * K * 2;
  char* gB0 = (char*)Bw + ((size_t)(n0 + row0) * K) * 2 + colb;
  char* gB1 = gB0 + (size_t)64 * K * 2;

  unsigned short* lA0 = lA + wave * 512;
  unsigned short* lA1 = lA + 2048 + wave * 512;
  unsigned short* lB0 = lB + wave * 512;
  unsigned short* lB1 = lB + 2048 + wave * 512;

  f32x4 acc[4][4];
#pragma unroll
  for (int i = 0; i < 4; i++)
#pragma unroll
    for (int j = 0; j < 4; j++) acc[i][j] = (f32x4){0.f, 0.f, 0.f, 0.f};

  const int fr  = lane & 15;
  const int fkb = (lane >> 4) * 16;
  const char* lab = (const char*)lA;
  const char* lbb = (const char*)lB;

  for (int k0 = 0; k0 < Keff; k0 += 32) {
    ASYNC16(gA0, lA0);
    ASYNC16(gA1, lA1);
    ASYNC16(gB0, lB0);
    ASYNC16(gB1, lB1);
    gA0 += 64; gA1 += 64; gB0 += 64; gB1 += 64;
    __syncthreads();

    s16x8 af[4], bfr[4];
#pragma unroll
    for (int i = 0; i < 4; i++)
      af[i] = *(const s16x8*)(lab + (wm + i * 16 + fr) * 64 + fkb);
#pragma unroll
    for (int i = 0; i < 4; i++)
      bfr[i] = *(const s16x8*)(lbb + (wn + i * 16 + fr) * 64 + fkb);

#pragma unroll
    for (int i = 0; i < 4; i++)
#pragma unroll
      for (int j = 0; j < 4; j++)
        acc[i][j] = __builtin_amdgcn_mfma_f32_16x16x32_bf16(af[i], bfr[j], acc[i][j], 0, 0, 0);
    __syncthreads();
  }

#pragma unroll
  for (int j = 0; j < 4; j++) {
    const int col = n0 + wn + j * 16 + fr;
    const float bv = bias[col];
#pragma unroll
    for (int i = 0; i < 4; i++) {
      const int rbase = m0 + wm + i * 16 + (lane >> 4) * 4;
#pragma unroll
      for (int r = 0; r < 4; r++) {
        float v = acc[i][j][r] + bv;
        if (relu) v = fmaxf(v, 0.0f);
        C[(size_t)(rbase + r) * N + col] = f2bf(v);
      }
    }
  }
}

// ---------------- spline math (per (b,d)) ----------------

__device__ __forceinline__ void rq_spline(const unsigned short* __restrict__ pp,
                                          float zv, float& zn, float& lad) {
  const float TAILC = 25.0f;
  const float MIN_WC = 0.001f;
  const float MIN_DC = 0.001f;
  const float SCALE = 0.044194173824159216f; // 1/sqrt(512)

  s16x8 vw = *(const s16x8*)(pp);
  s16x8 vh = *(const s16x8*)(pp + 8);
  s16x8 vd = *(const s16x8*)(pp + 16);

  bool inside = (zv >= -TAILC) && (zv <= TAILC);
  float z_in = fminf(fmaxf(zv, -TAILC), TAILC);

  // softmax without max-pass: params are ~±1.3; clamp to ±30 for safety.
  float ew[8], eh[8], sw = 0.f, sh = 0.f;
#pragma unroll
  for (int i = 0; i < 8; i++) {
    float u = fminf(fmaxf(bf2f((unsigned short)vw[i]) * SCALE, -30.f), 30.f);
    ew[i] = __expf(u); sw += ew[i];
  }
#pragma unroll
  for (int i = 0; i < 8; i++) {
    float u = fminf(fmaxf(bf2f((unsigned short)vh[i]) * SCALE, -30.f), 30.f);
    eh[i] = __expf(u); sh += eh[i];
  }
  float iw = (1.0f - 8.0f * MIN_WC) / sw;
  float ih = (1.0f - 8.0f * MIN_WC) / sh;

  float cumw[9], cumh[9];
  cumw[0] = -TAILC; cumh[0] = -TAILC;
  float cw = 0.f, ch = 0.f;
#pragma unroll
  for (int i = 0; i < 8; i++) {
    cw += MIN_WC + ew[i] * iw;
    ch += MIN_WC + eh[i] * ih;
    cumw[i + 1] = fmaf(2.0f * TAILC, cw, -TAILC);
    cumh[i + 1] = fmaf(2.0f * TAILC, ch, -TAILC);
  }
  cumw[8] = TAILC; cumh[8] = TAILC;

  int idx = 0;
#pragma unroll
  for (int i = 1; i < 8; i++) idx += (z_in >= cumw[i]) ? 1 : 0;

  float in_cw = 0.f, cw1 = 1.f, in_ch = 0.f, ch1 = 1.f, u0 = 0.f, u1 = 0.f;
#pragma unroll
  for (int i = 0; i < 8; i++) {
    if (i == idx) {
      in_cw = cumw[i]; cw1 = cumw[i + 1];
      in_ch = cumh[i]; ch1 = cumh[i + 1];
      u0 = (i > 0) ? bf2f((unsigned short)vd[i - 1]) : 0.0f;
      u1 = (i < 7) ? bf2f((unsigned short)vd[i]) : 0.0f;
    }
  }
  float dd0 = (idx == 0) ? 1.0f
            : MIN_DC + fmaxf(u0, 0.f) + __logf(1.0f + __expf(-fabsf(u0)));
  float dd1 = (idx == 7) ? 1.0f
            : MIN_DC + fmaxf(u1, 0.f) + __logf(1.0f + __expf(-fabsf(u1)));
  float in_w = cw1 - in_cw;
  float in_h = ch1 - in_ch;

  float delta = in_h / in_w;
  float th  = (z_in - in_cw) / in_w;
  float th1 = th * (1.0f - th);
  float th2 = th * th;
  float num = in_h * (delta * th2 + dd0 * th1);
  float den = delta + (dd0 + dd1 - 2.0f * delta) * th1;
  float outz = in_ch + num / den;
  float omt = 1.0f - th;
  float dnum = delta * delta * (dd1 * th2 + 2.0f * delta * th1 + dd0 * omt * omt);
  float l = __logf(dnum) - 2.0f * __logf(den);

  zn  = inside ? outz : zv;
  lad = inside ? l : 0.0f;
}

// ---------------- fused GEMM3 + spline, 128x192 tile, triangular K ----------------
// grid MUST be (8, 256). Block: 128 rows x 192 cols (8 dims). K_eff = 64*(bn+1).
// Spline epilogue in TWO 64-row halves; pT (64 rows) unioned over lA/lB ->
// LDS 25.6 KB -> 6 blocks/CU co-resident (GEMM-phase MFMA overlaps spline VALU).

__global__ __launch_bounds__(256, 6) void gemm3_spline(
    const unsigned short* __restrict__ A,     // h2 [B][512] (k degree-permuted)
    const unsigned short* __restrict__ Bw,    // w3c[t] [1536][512] (MPAD rows, perm k)
    const float* __restrict__ bias,           // [1536] (MPAD layout)
    float* __restrict__ curf,                 // [B][64]
    unsigned short* __restrict__ A1,          // [B][320]
    float* __restrict__ lad_acc)              // [B]
{
  __shared__ alignas(16) union {
    struct { unsigned short A[128 * 32]; unsigned short B[192 * 32]; } g;
    unsigned short p[64 * PSTRIDE];
  } sm;

  const int tid  = threadIdx.x;
  const int lane = tid & 63;
  const int wave = tid >> 6;

  const int lin = blockIdx.y * 8 + blockIdx.x;
  const int xcd = lin & 7;
  const int loc = lin >> 3;
  const int m0 = (xcd * 32 + (loc >> 3)) * 128;
  const int bn = loc & 7;
  const int n0 = bn * 192;
  const int Keff = 64 * (bn + 1);   // dims 8bn..8bn+7 need h_deg <= 8bn+7

  const int wm = (wave >> 1) * 64;
  const int wn = (wave & 1) * 96;
  const int fr = lane & 15;

  // spline-phase indices (4 threads/row, 2 dims each) + prefetch both halves
  const int row64 = tid >> 2;
  const int dl0 = (tid & 3) * 2;
  const int d0 = bn * 8 + dl0;
  float2 cz0 = *(const float2*)(curf + (size_t)(m0 + row64) * ZD + d0);
  float2 cz1 = *(const float2*)(curf + (size_t)(m0 + 64 + row64) * ZD + d0);
  float bv[6];
#pragma unroll
  for (int j = 0; j < 6; j++) bv[j] = bias[n0 + wn + j * 16 + fr];

  const int f    = tid * 16;
  const int row0 = f >> 6;
  const int colb = f & 63;
  const int K = HID;

  char* gA0 = (char*)A  + ((size_t)(m0 + row0) * K) * 2 + colb;
  char* gA1 = gA0 + (size_t)64 * K * 2;
  char* gB0 = (char*)Bw + ((size_t)(n0 + row0) * K) * 2 + colb;
  char* gB1 = gB0 + (size_t)64 * K * 2;
  char* gB2 = gB1 + (size_t)64 * K * 2;

  unsigned short* lA0 = sm.g.A + wave * 512;
  unsigned short* lA1 = sm.g.A + 2048 + wave * 512;
  unsigned short* lB0 = sm.g.B + wave * 512;
  unsigned short* lB1 = sm.g.B + 2048 + wave * 512;
  unsigned short* lB2 = sm.g.B + 4096 + wave * 512;

  f32x4 acc[4][6];
#pragma unroll
  for (int i = 0; i < 4; i++)
#pragma unroll
    for (int j = 0; j < 6; j++) acc[i][j] = (f32x4){0.f, 0.f, 0.f, 0.f};

  const int fkb = (lane >> 4) * 16;
  const char* lab = (const char*)sm.g.A;
  const char* lbb = (const char*)sm.g.B;

  for (int k0 = 0; k0 < Keff; k0 += 32) {
    ASYNC16(gA0, lA0);
    ASYNC16(gA1, lA1);
    ASYNC16(gB0, lB0);
    ASYNC16(gB1, lB1);
    ASYNC16(gB2, lB2);
    gA0 += 64; gA1 += 64; gB0 += 64; gB1 += 64; gB2 += 64;
    __syncthreads();

    s16x8 af[4], bfr[6];
#pragma unroll
    for (int i = 0; i < 4; i++)
      af[i] = *(const s16x8*)(lab + (wm + i * 16 + fr) * 64 + fkb);
#pragma unroll
    for (int j = 0; j < 6; j++)
      bfr[j] = *(const s16x8*)(lbb + (wn + j * 16 + fr) * 64 + fkb);

#pragma unroll
    for (int i = 0; i < 4; i++)
#pragma unroll
      for (int j = 0; j < 6; j++)
        acc[i][j] = __builtin_amdgcn_mfma_f32_16x16x32_bf16(af[i], bfr[j], acc[i][j], 0, 0, 0);
    __syncthreads();
  }

  // two-half epilogue: waves (wave>>1)==h dump acc to pT, then all threads spline
  float ladsum0 = 0.f, ladsum1 = 0.f;
#pragma unroll
  for (int h = 0; h < 2; h++) {
    if ((wave >> 1) == h) {
#pragma unroll
      for (int j = 0; j < 6; j++) {
        const int col = wn + j * 16 + fr;
#pragma unroll
        for (int i = 0; i < 4; i++) {
          const int rloc = i * 16 + (lane >> 4) * 4;
#pragma unroll
          for (int r = 0; r < 4; r++)
            sm.p[(rloc + r) * PSTRIDE + col] = f2bf(acc[i][j][r] + bv[j]);
        }
      }
    }
    __syncthreads();

    const unsigned short* pp = sm.p + row64 * PSTRIDE + dl0 * MPAD;
    float2 cz = h ? cz1 : cz0;
    const int sb = m0 + h * 64 + row64;
    float zn0, zn1, l0, l1;
    rq_spline(pp,        cz.x, zn0, l0);
    rq_spline(pp + MPAD, cz.y, zn1, l1);

    *(float2*)(curf + (size_t)sb * ZD + d0) = make_float2(zn0, zn1);
    unsigned int packed = (unsigned int)f2bf(zn0) | ((unsigned int)f2bf(zn1) << 16);
    *(unsigned int*)(A1 + (size_t)sb * K1 + d0) = packed;

    if (h) ladsum1 = l0 + l1; else ladsum0 = l0 + l1;
    if (h == 0) __syncthreads();   // protect pT before half-1 overwrite
  }

  // lad reduction: 4 threads/row -> 1 atomic per row per half
  float s0 = ladsum0;
  s0 += __shfl_xor(s0, 1, 64);
  s0 += __shfl_xor(s0, 2, 64);
  float s1 = ladsum1;
  s1 += __shfl_xor(s1, 1, 64);
  s1 += __shfl_xor(s1, 2, 64);
  if ((tid & 3) == 0) {
    atomicAdd(&lad_acc[m0 + row64], s0);
    atomicAdd(&lad_acc[m0 + 64 + row64], s1);
  }
}

// ---------------- finalize ----------------

__global__ void finalize(const float* __restrict__ curf, const float* __restrict__ lad,
                         float* __restrict__ out) {
  int i = blockIdx.x * 256 + threadIdx.x;
  int b = i >> 6;
  int d = i & 63;
  float c = curf[i];
  float q = c * c;
#pragma unroll
  for (int off = 32; off > 0; off >>= 1) q += __shfl_xor(q, off, 64);
  if (d == 0) out[b] = lad[b] - 0.5f * q - 58.81206612509905f;
}

// ---------------- launch ----------------

extern "C" void kernel_launch(void* const* d_in, const int* in_sizes, int n_in,
                              void* d_out, int out_size, void* d_ws, size_t ws_size,
                              hipStream_t stream)
{
  const float* z  = (const float*)d_in[0];
  const float* x  = (const float*)d_in[1];
  const float* W1 = (const float*)d_in[2];
  const float* b1 = (const float*)d_in[3];
  const float* Wc = (const float*)d_in[4];
  const float* bc = (const float*)d_in[5];
  const float* W2 = (const float*)d_in[6];
  const float* b2 = (const float*)d_in[7];
  const float* W3 = (const float*)d_in[8];
  const float* b3 = (const float*)d_in[9];
  float* out = (float*)d_out;
  char* ws = (char*)d_ws;

  size_t oA1 = 0;
  size_t oH1 = oA1 + (size_t)B_ROWS * K1 * 2;
  size_t oH2 = oH1 + (size_t)B_ROWS * HID * 2;
  size_t oCU = oH2 + (size_t)B_ROWS * HID * 2;
  size_t oLA = oCU + (size_t)B_ROWS * ZD * 4;
  size_t oW1 = oLA + (size_t)B_ROWS * 4;
  size_t oW2 = oW1 + (size_t)T_STEPS * HID * K1 * 2;
  size_t oW3 = oW2 + (size_t)T_STEPS * HID * HID * 2;
  size_t oB1 = oW3 + (size_t)T_STEPS * NPAD * HID * 2;
  size_t oB2 = oB1 + (size_t)T_STEPS * HID * 4;
  size_t oB3 = oB2 + (size_t)T_STEPS * HID * 4;

  unsigned short* A1  = (unsigned short*)(ws + oA1);
  unsigned short* h1  = (unsigned short*)(ws + oH1);
  unsigned short* h2  = (unsigned short*)(ws + oH2);
  float* curf = (float*)(ws + oCU);
  float* lad  = (float*)(ws + oLA);
  unsigned short* w1c = (unsigned short*)(ws + oW1);
  unsigned short* w2c = (unsigned short*)(ws + oW2);
  unsigned short* w3c = (unsigned short*)(ws + oW3);
  float* b1c = (float*)(ws + oB1);
  float* b2p = (float*)(ws + oB2);
  float* b3c = (float*)(ws + oB3);

  prep_w1cat<<<T_STEPS * HID * K1 / 256, 256, 0, stream>>>(W1, Wc, w1c);
  prep_w2<<<T_STEPS * HID * HID / 256, 256, 0, stream>>>(W2, w2c);
  prep_w3<<<T_STEPS * NPAD * HID / 256, 256, 0, stream>>>(W3, w3c);
  prep_bias<<<T_STEPS * (2 * HID + NPAD) / 256, 256, 0, stream>>>(
      b1, bc, b2, b3, b1c, b2p, b3c);
  prep_x<<<B_ROWS * XD / 256, 256, 0, stream>>>(x, A1);
  prep_init<<<B_ROWS * ZD / 256, 256, 0, stream>>>(z, A1, curf, lad);

  for (int t = 0; t < T_STEPS; ++t) {
    gemm_bias<<<dim3(4, B_ROWS / 128), 256, 0, stream>>>(
        A1, w1c + (size_t)t * HID * K1, b1c + (size_t)t * HID, h1,
        B_ROWS, HID, K1, 0, 0);
    gemm_bias<<<dim3(4, B_ROWS / 128), 256, 0, stream>>>(
        h1, w2c + (size_t)t * HID * HID, b2p + (size_t)t * HID, h2,
        B_ROWS, HID, HID, 1, 1);
    gemm3_spline<<<dim3(8, B_ROWS / 128), 256, 0, stream>>>(
        h2, w3c + (size_t)t * NPAD * HID, b3c + (size_t)t * NPAD,
        curf, A1, lad);
  }
  finalize<<<B_ROWS * ZD / 256, 256, 0, stream>>>(curf, lad, out);
}

// Round 6
// 988.624 us; speedup vs baseline: 6.9434x; 6.9434x over previous
//
#include <hip/hip_runtime.h>
#include <cstdint>
#include <cstddef>

#define B_ROWS 32768
#define ZD 64
#define XD 256
#define HID 512
#define T_STEPS 8
#define MULT 23
#define MPAD 24
#define NOUT 1472
#define NPAD 1536      // 64 * MPAD
#define K1 320         // ZD + XD
#define PSTRIDE 200    // padded row stride (ushorts) for p-tile in LDS (400B = 25*16B)

typedef float f32x4 __attribute__((ext_vector_type(4)));
typedef short s16x8 __attribute__((ext_vector_type(8)));

__device__ __forceinline__ unsigned short f2bf(float f) {
  unsigned int u = __float_as_uint(f);
  u = (u + 0x7FFFu + ((u >> 16) & 1u)) >> 16;   // RNE, no NaN inputs here
  return (unsigned short)u;
}
__device__ __forceinline__ float bf2f(unsigned short s) {
  return __uint_as_float(((unsigned int)s) << 16);
}

// Degree-sort permutation of the hidden dim. deg(i) = (i%63)+1; count(g) = 9 (g<=8) else 8.
__device__ __forceinline__ int permP(int n) {
  return (n < 72) ? (n / 9) + 63 * (n % 9)
                  : ((n - 72) >> 3) + 8 + 63 * ((n - 72) & 7);
}
__device__ __forceinline__ int degP(int n) {
  return (n < 72) ? (n / 9) + 1 : ((n - 72) >> 3) + 9;
}

// ---------------- prep kernels (masks folded, degree-permuted, bf16) ----------------

__global__ void prep_w1cat(const float* __restrict__ W1, const float* __restrict__ Wc,
                           unsigned short* __restrict__ o) {
  int i = blockIdx.x * 256 + threadIdx.x;
  if (i >= T_STEPS * HID * K1) return;
  int t = i / (HID * K1);
  int r = i - t * (HID * K1);
  int n = r / K1;          // permuted hidden row
  int k = r - n * K1;
  int on = permP(n);
  float v;
  if (k < ZD) {  // m1: h_deg >= z_deg  <->  (on%63) >= k
    v = ((on % 63) >= k) ? W1[((size_t)t * HID + on) * ZD + k] : 0.0f;
  } else {
    v = Wc[((size_t)t * HID + on) * XD + (k - ZD)];
  }
  o[i] = f2bf(v);
}

__global__ void prep_w2(const float* __restrict__ W2, unsigned short* __restrict__ o) {
  int i = blockIdx.x * 256 + threadIdx.x;
  if (i >= T_STEPS * HID * HID) return;
  int t = i / (HID * HID);
  int r = i - t * (HID * HID);
  int n = r / HID;         // permuted out
  int k = r - n * HID;     // permuted in
  float v = 0.0f;
  if (degP(n) >= degP(k))  // m2: out_deg >= in_deg
    v = W2[((size_t)t * HID + permP(n)) * HID + permP(k)];
  o[i] = f2bf(v);
}

// W3: MPAD=24 row layout (row n = d*24 + jj, jj==23 zero), columns degree-permuted.
__global__ void prep_w3(const float* __restrict__ W3, unsigned short* __restrict__ o) {
  int i = blockIdx.x * 256 + threadIdx.x;
  if (i >= T_STEPS * NPAD * HID) return;
  int t = i / (NPAD * HID);
  int r = i - t * (NPAD * HID);
  int n = r / HID;
  int k = r - n * HID;     // permuted in
  int d = n / MPAD;
  int jj = n - d * MPAD;
  float v = 0.0f;
  if (jj < MULT && d >= degP(k))   // m3: o_deg(d+1) > h_deg  <->  h_deg <= d
    v = W3[((size_t)t * NOUT + d * MULT + jj) * HID + permP(k)];
  o[i] = f2bf(v);
}

__global__ void prep_bias(const float* __restrict__ b1, const float* __restrict__ bc,
                          const float* __restrict__ b2, const float* __restrict__ b3,
                          float* __restrict__ ob1, float* __restrict__ ob2,
                          float* __restrict__ ob3) {
  int i = blockIdx.x * 256 + threadIdx.x;
  if (i < T_STEPS * HID) {
    int t = i / HID, n = i - t * HID;
    int on = permP(n);
    ob1[i] = b1[(size_t)t * HID + on] + bc[(size_t)t * HID + on];
  } else if (i < 2 * T_STEPS * HID) {
    int j = i - T_STEPS * HID;
    int t = j / HID, n = j - t * HID;
    ob2[j] = b2[(size_t)t * HID + permP(n)];
  } else {
    int j = i - 2 * T_STEPS * HID;
    if (j < T_STEPS * NPAD) {
      int t = j / NPAD;
      int n = j - t * NPAD;
      int d = n / MPAD;
      int jj = n - d * MPAD;
      ob3[j] = (jj < MULT) ? b3[(size_t)t * NOUT + d * MULT + jj] : 0.0f;
    }
  }
}

__global__ void prep_x(const float* __restrict__ x, unsigned short* __restrict__ A1) {
  int i = blockIdx.x * 256 + threadIdx.x;
  if (i >= B_ROWS * XD) return;
  int b = i >> 8;
  int j = i & 255;
  A1[(size_t)b * K1 + ZD + j] = f2bf(x[i]);
}

__global__ void prep_init(const float* __restrict__ z, unsigned short* __restrict__ A1,
                          float* __restrict__ curf, float* __restrict__ lad) {
  int i = blockIdx.x * 256 + threadIdx.x;
  if (i >= B_ROWS * ZD) return;
  int b = i >> 6;
  int d = i & 63;
  float zv = z[i];
  A1[(size_t)b * K1 + d] = f2bf(zv);
  curf[i] = zv;
  if (d == 0) lad[b] = 0.0f;
}

// ---------------- shared GEMM machinery ----------------

#define ASYNC16(gp, lp) __builtin_amdgcn_global_load_lds( \
    (__attribute__((address_space(1))) unsigned int*)(gp), \
    (__attribute__((address_space(3))) unsigned int*)(lp), 16, 0, 0)

// ---------------- GEMM1/2: C[M,512] = A[M,K]@W[512,K]^T + bias, opt relu ----------
// grid MUST be (4, 256). tri=1: triangular K_eff = min(K, 192+n0) (gemm2 schedule).

__global__ __launch_bounds__(256, 2) void gemm_bias(
    const unsigned short* __restrict__ A,
    const unsigned short* __restrict__ Bw,
    const float* __restrict__ bias,
    unsigned short* __restrict__ C,
    int M, int N, int K, int relu, int tri)
{
  __shared__ alignas(16) unsigned short lA[128 * 32];
  __shared__ alignas(16) unsigned short lB[128 * 32];

  const int tid  = threadIdx.x;
  const int lane = tid & 63;
  const int wave = tid >> 6;

  const int lin = blockIdx.y * 4 + blockIdx.x;
  const int xcd = lin & 7;
  const int loc = lin >> 3;
  const int m0 = (xcd * 32 + (loc >> 2)) * 128;
  const int n0 = (loc & 3) * 128;
  const int Keff = tri ? min(K, 192 + n0) : K;

  const int wm = (wave >> 1) * 64;
  const int wn = (wave & 1) * 64;

  const int f    = tid * 16;
  const int row0 = f >> 6;       // 64B per 32-elem row
  const int colb = f & 63;

  char* gA0 = (char*)A  + ((size_t)(m0 + row0) * K) * 2 + colb;
  char* gA1 = gA0 + (size_t)64 * K * 2;
  char* gB0 = (char*)Bw + ((size_t)(n0 + row0) * K) * 2 + colb;
  char* gB1 = gB0 + (size_t)64 * K * 2;

  unsigned short* lA0 = lA + wave * 512;
  unsigned short* lA1 = lA + 2048 + wave * 512;
  unsigned short* lB0 = lB + wave * 512;
  unsigned short* lB1 = lB + 2048 + wave * 512;

  f32x4 acc[4][4];
#pragma unroll
  for (int i = 0; i < 4; i++)
#pragma unroll
    for (int j = 0; j < 4; j++) acc[i][j] = (f32x4){0.f, 0.f, 0.f, 0.f};

  const int fr  = lane & 15;
  const int fkb = (lane >> 4) * 16;
  const char* lab = (const char*)lA;
  const char* lbb = (const char*)lB;

  for (int k0 = 0; k0 < Keff; k0 += 32) {
    ASYNC16(gA0, lA0);
    ASYNC16(gA1, lA1);
    ASYNC16(gB0, lB0);
    ASYNC16(gB1, lB1);
    gA0 += 64; gA1 += 64; gB0 += 64; gB1 += 64;
    __syncthreads();

    s16x8 af[4], bfr[4];
#pragma unroll
    for (int i = 0; i < 4; i++)
      af[i] = *(const s16x8*)(lab + (wm + i * 16 + fr) * 64 + fkb);
#pragma unroll
    for (int i = 0; i < 4; i++)
      bfr[i] = *(const s16x8*)(lbb + (wn + i * 16 + fr) * 64 + fkb);

#pragma unroll
    for (int i = 0; i < 4; i++)
#pragma unroll
      for (int j = 0; j < 4; j++)
        acc[i][j] = __builtin_amdgcn_mfma_f32_16x16x32_bf16(af[i], bfr[j], acc[i][j], 0, 0, 0);
    __syncthreads();
  }

#pragma unroll
  for (int j = 0; j < 4; j++) {
    const int col = n0 + wn + j * 16 + fr;
    const float bv = bias[col];
#pragma unroll
    for (int i = 0; i < 4; i++) {
      const int rbase = m0 + wm + i * 16 + (lane >> 4) * 4;
#pragma unroll
      for (int r = 0; r < 4; r++) {
        float v = acc[i][j][r] + bv;
        if (relu) v = fmaxf(v, 0.0f);
        C[(size_t)(rbase + r) * N + col] = f2bf(v);
      }
    }
  }
}

// ---------------- spline math (per (b,d)) ----------------

__device__ __forceinline__ void rq_spline(const unsigned short* __restrict__ pp,
                                          float zv, float& zn, float& lad) {
  const float TAILC = 25.0f;
  const float MIN_WC = 0.001f;
  const float MIN_DC = 0.001f;
  const float SCALE = 0.044194173824159216f; // 1/sqrt(512)

  s16x8 vw = *(const s16x8*)(pp);
  s16x8 vh = *(const s16x8*)(pp + 8);
  s16x8 vd = *(const s16x8*)(pp + 16);

  bool inside = (zv >= -TAILC) && (zv <= TAILC);
  float z_in = fminf(fmaxf(zv, -TAILC), TAILC);

  // softmax without max-pass: params are ~±1.3; clamp to ±30 for safety.
  float ew[8], eh[8], sw = 0.f, sh = 0.f;
#pragma unroll
  for (int i = 0; i < 8; i++) {
    float u = fminf(fmaxf(bf2f((unsigned short)vw[i]) * SCALE, -30.f), 30.f);
    ew[i] = __expf(u); sw += ew[i];
  }
#pragma unroll
  for (int i = 0; i < 8; i++) {
    float u = fminf(fmaxf(bf2f((unsigned short)vh[i]) * SCALE, -30.f), 30.f);
    eh[i] = __expf(u); sh += eh[i];
  }
  float iw = (1.0f - 8.0f * MIN_WC) / sw;
  float ih = (1.0f - 8.0f * MIN_WC) / sh;

  float cumw[9], cumh[9];
  cumw[0] = -TAILC; cumh[0] = -TAILC;
  float cw = 0.f, ch = 0.f;
#pragma unroll
  for (int i = 0; i < 8; i++) {
    cw += MIN_WC + ew[i] * iw;
    ch += MIN_WC + eh[i] * ih;
    cumw[i + 1] = fmaf(2.0f * TAILC, cw, -TAILC);
    cumh[i + 1] = fmaf(2.0f * TAILC, ch, -TAILC);
  }
  cumw[8] = TAILC; cumh[8] = TAILC;

  int idx = 0;
#pragma unroll
  for (int i = 1; i < 8; i++) idx += (z_in >= cumw[i]) ? 1 : 0;

  float in_cw = 0.f, cw1 = 1.f, in_ch = 0.f, ch1 = 1.f, u0 = 0.f, u1 = 0.f;
#pragma unroll
  for (int i = 0; i < 8; i++) {
    if (i == idx) {
      in_cw = cumw[i]; cw1 = cumw[i + 1];
      in_ch = cumh[i]; ch1 = cumh[i + 1];
      u0 = (i > 0) ? bf2f((unsigned short)vd[i - 1]) : 0.0f;
      u1 = (i < 7) ? bf2f((unsigned short)vd[i]) : 0.0f;
    }
  }
  float dd0 = (idx == 0) ? 1.0f
            : MIN_DC + fmaxf(u0, 0.f) + __logf(1.0f + __expf(-fabsf(u0)));
  float dd1 = (idx == 7) ? 1.0f
            : MIN_DC + fmaxf(u1, 0.f) + __logf(1.0f + __expf(-fabsf(u1)));
  float in_w = cw1 - in_cw;
  float in_h = ch1 - in_ch;

  float delta = in_h / in_w;
  float th  = (z_in - in_cw) / in_w;
  float th1 = th * (1.0f - th);
  float th2 = th * th;
  float num = in_h * (delta * th2 + dd0 * th1);
  float den = delta + (dd0 + dd1 - 2.0f * delta) * th1;
  float outz = in_ch + num / den;
  float omt = 1.0f - th;
  float dnum = delta * delta * (dd1 * th2 + 2.0f * delta * th1 + dd0 * omt * omt);
  float l = __logf(dnum) - 2.0f * __logf(den);

  zn  = inside ? outz : zv;
  lad = inside ? l : 0.0f;
}

// ---------------- fused GEMM3 + spline, 64x192 tile, triangular K ----------------
// grid MUST be (8, 512). Tile: 64 rows x 192 cols (8 dims). K_eff = 64*(bn+1).
// acc[4][3] = 48 regs/wave -> ~100 total incl arch; LDS 25.6 KB (pT unioned).
// launch_bounds(256,4): VGPR cap 128 — fits, NO spill (R5 lesson: (256,6) cap 85 spilled).

__global__ __launch_bounds__(256, 4) void gemm3_spline(
    const unsigned short* __restrict__ A,     // h2 [B][512] (k degree-permuted)
    const unsigned short* __restrict__ Bw,    // w3c[t] [1536][512] (MPAD rows, perm k)
    const float* __restrict__ bias,           // [1536] (MPAD layout)
    float* __restrict__ curf,                 // [B][64]
    unsigned short* __restrict__ A1,          // [B][320]
    float* __restrict__ lad_acc)              // [B]
{
  __shared__ alignas(16) union {
    struct { unsigned short A[64 * 32]; unsigned short B[192 * 32]; } g;
    unsigned short p[64 * PSTRIDE];
  } sm;

  const int tid  = threadIdx.x;
  const int lane = tid & 63;
  const int wave = tid >> 6;

  // swizzle for grid (8,512): lin%8 -> XCD; each XCD owns 64 consecutive m-strips.
  const int lin = blockIdx.y * 8 + blockIdx.x;
  const int xcd = lin & 7;
  const int loc = lin >> 3;
  const int m0 = (xcd * 64 + (loc >> 3)) * 64;
  const int bn = loc & 7;
  const int n0 = bn * 192;
  const int Keff = 64 * (bn + 1);   // dims 8bn..8bn+7 need h_deg <= 8bn+7

  const int wn = wave * 48;
  const int fr = lane & 15;

  // spline-phase indices (4 threads/row, 2 dims each) + prefetch
  const int row = tid >> 2;
  const int sb = m0 + row;
  const int dl0 = (tid & 3) * 2;
  const int d0 = bn * 8 + dl0;
  float2 cz = *(const float2*)(curf + (size_t)sb * ZD + d0);
  float bv[3];
#pragma unroll
  for (int j = 0; j < 3; j++) bv[j] = bias[n0 + wn + j * 16 + fr];

  const int f    = tid * 16;
  const int row0 = f >> 6;
  const int colb = f & 63;
  const int K = HID;

  char* gA0 = (char*)A  + ((size_t)(m0 + row0) * K) * 2 + colb;
  char* gB0 = (char*)Bw + ((size_t)(n0 + row0) * K) * 2 + colb;
  char* gB1 = gB0 + (size_t)64 * K * 2;
  char* gB2 = gB1 + (size_t)64 * K * 2;

  unsigned short* lA0 = sm.g.A + wave * 512;
  unsigned short* lB0 = sm.g.B + wave * 512;
  unsigned short* lB1 = sm.g.B + 2048 + wave * 512;
  unsigned short* lB2 = sm.g.B + 4096 + wave * 512;

  f32x4 acc[4][3];
#pragma unroll
  for (int i = 0; i < 4; i++)
#pragma unroll
    for (int j = 0; j < 3; j++) acc[i][j] = (f32x4){0.f, 0.f, 0.f, 0.f};

  const int fk = (lane >> 4) * 8;   // k offset in shorts

  for (int k0 = 0; k0 < Keff; k0 += 32) {
    ASYNC16(gA0, lA0);
    ASYNC16(gB0, lB0);
    ASYNC16(gB1, lB1);
    ASYNC16(gB2, lB2);
    gA0 += 64; gB0 += 64; gB1 += 64; gB2 += 64;
    __syncthreads();

    s16x8 af[4], bfr[3];
#pragma unroll
    for (int i = 0; i < 4; i++)
      af[i] = *(const s16x8*)(sm.g.A + (i * 16 + fr) * 32 + fk);
#pragma unroll
    for (int j = 0; j < 3; j++)
      bfr[j] = *(const s16x8*)(sm.g.B + (wn + j * 16 + fr) * 32 + fk);

#pragma unroll
    for (int i = 0; i < 4; i++)
#pragma unroll
      for (int j = 0; j < 3; j++)
        acc[i][j] = __builtin_amdgcn_mfma_f32_16x16x32_bf16(af[i], bfr[j], acc[i][j], 0, 0, 0);
    __syncthreads();
  }

  // accumulator + bias -> pT (bf16, padded stride); loop ended with barrier
#pragma unroll
  for (int j = 0; j < 3; j++) {
    const int col = wn + j * 16 + fr;
#pragma unroll
    for (int i = 0; i < 4; i++) {
      const int rbase = i * 16 + (lane >> 4) * 4;
#pragma unroll
      for (int r = 0; r < 4; r++)
        sm.p[(rbase + r) * PSTRIDE + col] = f2bf(acc[i][j][r] + bv[j]);
    }
  }
  __syncthreads();

  // spline: 4 threads per row, 2 dims each
  const unsigned short* pp = sm.p + row * PSTRIDE + dl0 * MPAD;
  float zn0, zn1, l0, l1;
  rq_spline(pp,        cz.x, zn0, l0);
  rq_spline(pp + MPAD, cz.y, zn1, l1);

  *(float2*)(curf + (size_t)sb * ZD + d0) = make_float2(zn0, zn1);
  unsigned int packed = (unsigned int)f2bf(zn0) | ((unsigned int)f2bf(zn1) << 16);
  *(unsigned int*)(A1 + (size_t)sb * K1 + d0) = packed;

  float s = l0 + l1;
  s += __shfl_xor(s, 1, 64);
  s += __shfl_xor(s, 2, 64);
  if ((tid & 3) == 0) atomicAdd(&lad_acc[sb], s);
}

// ---------------- finalize ----------------

__global__ void finalize(const float* __restrict__ curf, const float* __restrict__ lad,
                         float* __restrict__ out) {
  int i = blockIdx.x * 256 + threadIdx.x;
  int b = i >> 6;
  int d = i & 63;
  float c = curf[i];
  float q = c * c;
#pragma unroll
  for (int off = 32; off > 0; off >>= 1) q += __shfl_xor(q, off, 64);
  if (d == 0) out[b] = lad[b] - 0.5f * q - 58.81206612509905f;
}

// ---------------- launch ----------------

extern "C" void kernel_launch(void* const* d_in, const int* in_sizes, int n_in,
                              void* d_out, int out_size, void* d_ws, size_t ws_size,
                              hipStream_t stream)
{
  const float* z  = (const float*)d_in[0];
  const float* x  = (const float*)d_in[1];
  const float* W1 = (const float*)d_in[2];
  const float* b1 = (const float*)d_in[3];
  const float* Wc = (const float*)d_in[4];
  const float* bc = (const float*)d_in[5];
  const float* W2 = (const float*)d_in[6];
  const float* b2 = (const float*)d_in[7];
  const float* W3 = (const float*)d_in[8];
  const float* b3 = (const float*)d_in[9];
  float* out = (float*)d_out;
  char* ws = (char*)d_ws;

  size_t oA1 = 0;
  size_t oH1 = oA1 + (size_t)B_ROWS * K1 * 2;
  size_t oH2 = oH1 + (size_t)B_ROWS * HID * 2;
  size_t oCU = oH2 + (size_t)B_ROWS * HID * 2;
  size_t oLA = oCU + (size_t)B_ROWS * ZD * 4;
  size_t oW1 = oLA + (size_t)B_ROWS * 4;
  size_t oW2 = oW1 + (size_t)T_STEPS * HID * K1 * 2;
  size_t oW3 = oW2 + (size_t)T_STEPS * HID * HID * 2;
  size_t oB1 = oW3 + (size_t)T_STEPS * NPAD * HID * 2;
  size_t oB2 = oB1 + (size_t)T_STEPS * HID * 4;
  size_t oB3 = oB2 + (size_t)T_STEPS * HID * 4;

  unsigned short* A1  = (unsigned short*)(ws + oA1);
  unsigned short* h1  = (unsigned short*)(ws + oH1);
  unsigned short* h2  = (unsigned short*)(ws + oH2);
  float* curf = (float*)(ws + oCU);
  float* lad  = (float*)(ws + oLA);
  unsigned short* w1c = (unsigned short*)(ws + oW1);
  unsigned short* w2c = (unsigned short*)(ws + oW2);
  unsigned short* w3c = (unsigned short*)(ws + oW3);
  float* b1c = (float*)(ws + oB1);
  float* b2p = (float*)(ws + oB2);
  float* b3c = (float*)(ws + oB3);

  prep_w1cat<<<T_STEPS * HID * K1 / 256, 256, 0, stream>>>(W1, Wc, w1c);
  prep_w2<<<T_STEPS * HID * HID / 256, 256, 0, stream>>>(W2, w2c);
  prep_w3<<<T_STEPS * NPAD * HID / 256, 256, 0, stream>>>(W3, w3c);
  prep_bias<<<T_STEPS * (2 * HID + NPAD) / 256, 256, 0, stream>>>(
      b1, bc, b2, b3, b1c, b2p, b3c);
  prep_x<<<B_ROWS * XD / 256, 256, 0, stream>>>(x, A1);
  prep_init<<<B_ROWS * ZD / 256, 256, 0, stream>>>(z, A1, curf, lad);

  for (int t = 0; t < T_STEPS; ++t) {
    gemm_bias<<<dim3(4, B_ROWS / 128), 256, 0, stream>>>(
        A1, w1c + (size_t)t * HID * K1, b1c + (size_t)t * HID, h1,
        B_ROWS, HID, K1, 0, 0);
    gemm_bias<<<dim3(4, B_ROWS / 128), 256, 0, stream>>>(
        h1, w2c + (size_t)t * HID * HID, b2p + (size_t)t * HID, h2,
        B_ROWS, HID, HID, 1, 1);
    gemm3_spline<<<dim3(8, B_ROWS / 64), 256, 0, stream>>>(
        h2, w3c + (size_t)t * NPAD * HID, b3c + (size_t)t * NPAD,
        curf, A1, lad);
  }
  finalize<<<B_ROWS * ZD / 256, 256, 0, stream>>>(curf, lad, out);
}